// Round 2
// baseline (306.369 us; speedup 1.0000x reference)
//
#include <hip/hip_runtime.h>
#include <hip/hip_bf16.h>

typedef short s16x8 __attribute__((ext_vector_type(8)));
typedef float f32x4 __attribute__((ext_vector_type(4)));

#define S_LEN 2048
#define DMODEL 1024
#define NHEAD 16
#define HDIM 64
#define OUT_ELEMS 4194304   // B*S*D
#define HEAD_ELEMS 4194304  // B*H*S*HD

__device__ inline short f2bf(float f) {
  __hip_bfloat16 h = __float2bfloat16(f);  // RNE on gfx950
  return __builtin_bit_cast(short, h);
}

__device__ inline f32x4 mfma16(s16x8 a, s16x8 b, f32x4 c) {
  return __builtin_amdgcn_mfma_f32_16x16x32_bf16(a, b, c, 0, 0, 0);
}

// ---- convert+transpose: in [batch][R][C] f32 -> out [batch][C][R] bf16 ----
__global__ __launch_bounds__(256) void transpose_cvt(
    const float* __restrict__ in, short* __restrict__ out, int R, int C) {
  size_t mat = (size_t)R * C;
  const float* ib = in + (size_t)blockIdx.y * mat;
  short* ob = out + (size_t)blockIdx.y * mat;
  int g = blockIdx.x * 256 + threadIdx.x;
  int c = g % C;
  int r0 = (g / C) * 8;
  s16x8 v;
#pragma unroll
  for (int j = 0; j < 8; j++) v[j] = f2bf(ib[(size_t)(r0 + j) * C + c]);
  *(s16x8*)&ob[(size_t)c * R + r0] = v;
}

// ---- GEMM: C = A[M,K] * Bt[N,K]^T + bias. A f32 or bf16; Bt bf16. ---------
// MODE 0: QKV scatter: part0 -> Ob0 (Q, bf16 ws), part1/2 -> Of (present, f32)
// MODE 1: plain f32 row-major store to Of
template <int MODE, bool AF32>
__global__ __launch_bounds__(256) void gemm_bt(
    const void* __restrict__ Araw, const short* __restrict__ Bt,
    const float* __restrict__ bias, short* __restrict__ Ob0,
    float* __restrict__ Of, int M, int N, int K) {
  __shared__ short As[128][40];
  __shared__ short Bs[128][40];
  const int t = threadIdx.x;
  const int lane = t & 63;
  const int wid = t >> 6;
  const int wr = wid >> 1, wc = wid & 1;
  const int l16 = lane & 15, lg = lane >> 4;
  const int mbase = blockIdx.y * 128;
  const int nbase = blockIdx.x * 128;

  f32x4 acc[4][4];
#pragma unroll
  for (int m = 0; m < 4; m++)
#pragma unroll
    for (int n = 0; n < 4; n++) acc[m][n] = (f32x4){0.f, 0.f, 0.f, 0.f};

  const int srow = t >> 2;      // 0..63
  const int skc = (t & 3) * 8;  // 0,8,16,24

  for (int k0 = 0; k0 < K; k0 += 32) {
    s16x8 a0, a1;
    if constexpr (AF32) {
      const float* Af = (const float*)Araw;
      const float* p0 = &Af[(size_t)(mbase + srow) * K + k0 + skc];
      const float* p1 = &Af[(size_t)(mbase + srow + 64) * K + k0 + skc];
      f32x4 x00 = *(const f32x4*)p0, x01 = *(const f32x4*)(p0 + 4);
      f32x4 x10 = *(const f32x4*)p1, x11 = *(const f32x4*)(p1 + 4);
#pragma unroll
      for (int j = 0; j < 4; j++) {
        a0[j] = f2bf(x00[j]); a0[4 + j] = f2bf(x01[j]);
        a1[j] = f2bf(x10[j]); a1[4 + j] = f2bf(x11[j]);
      }
    } else {
      const short* Ab = (const short*)Araw;
      a0 = *(const s16x8*)&Ab[(size_t)(mbase + srow) * K + k0 + skc];
      a1 = *(const s16x8*)&Ab[(size_t)(mbase + srow + 64) * K + k0 + skc];
    }
    s16x8 b0 = *(const s16x8*)&Bt[(size_t)(nbase + srow) * K + k0 + skc];
    s16x8 b1 = *(const s16x8*)&Bt[(size_t)(nbase + srow + 64) * K + k0 + skc];
    __syncthreads();
    *(s16x8*)&As[srow][skc] = a0;
    *(s16x8*)&As[srow + 64][skc] = a1;
    *(s16x8*)&Bs[srow][skc] = b0;
    *(s16x8*)&Bs[srow + 64][skc] = b1;
    __syncthreads();
    s16x8 af[4], bfr[4];
#pragma unroll
    for (int m = 0; m < 4; m++)
      af[m] = *(const s16x8*)&As[wr * 64 + m * 16 + l16][lg * 8];
#pragma unroll
    for (int n = 0; n < 4; n++)
      bfr[n] = *(const s16x8*)&Bs[wc * 64 + n * 16 + l16][lg * 8];
#pragma unroll
    for (int m = 0; m < 4; m++)
#pragma unroll
      for (int n = 0; n < 4; n++)
        acc[m][n] = mfma16(af[m], bfr[n], acc[m][n]);
  }

#pragma unroll
  for (int m = 0; m < 4; m++) {
#pragma unroll
    for (int n = 0; n < 4; n++) {
      int gcol = nbase + wc * 64 + n * 16 + l16;
      float bv = bias[gcol];
      int part = gcol >> 10;
      int cin = gcol & 1023;
      int h = cin >> 6, hd = cin & 63;
#pragma unroll
      for (int r = 0; r < 4; r++) {
        int grow = mbase + wr * 64 + m * 16 + lg * 4 + r;
        float v = acc[m][n][r] + bv;
        if (MODE == 0) {
          int bb = grow >> 11, s = grow & 2047;
          size_t idx = ((size_t)(bb * NHEAD + h) * S_LEN + s) * HDIM + hd;
          if (part == 0)
            Ob0[idx] = f2bf(v);
          else if (part == 1)
            Of[idx] = v;
          else
            Of[HEAD_ELEMS + idx] = v;
        } else {
          Of[(size_t)grow * N + gcol] = v;
        }
      }
    }
  }
}

// ---- causal flash attention -------------------------------------------------
// Q: bf16 [bh][S][64] (ws), Kf: f32 present-k [bh][S][64] (d_out),
// Vt: bf16 [bh][64][S] (ws), AO: bf16 [B][S][D] (ws)
__global__ __launch_bounds__(256) void attn_fwd(
    const short* __restrict__ Q, const float* __restrict__ Kf,
    const short* __restrict__ Vt, short* __restrict__ AO) {
  __shared__ short P_lds[4][16 * 72];
  const int bh = blockIdx.x;
  const int qblk = blockIdx.y;
  const int tid = threadIdx.x;
  const int w = tid >> 6;
  const int lane = tid & 63;
  const int l16 = lane & 15;
  const int lg = lane >> 4;
  const int qb = qblk * 64 + w * 16;

  const short* Qb = Q + (size_t)bh * S_LEN * HDIM;
  const float* Kb = Kf + (size_t)bh * S_LEN * HDIM;
  const short* Vb = Vt + (size_t)bh * HDIM * S_LEN;

  s16x8 aq0 = *(const s16x8*)&Qb[(size_t)(qb + l16) * HDIM + lg * 8];
  s16x8 aq1 = *(const s16x8*)&Qb[(size_t)(qb + l16) * HDIM + 32 + lg * 8];

  f32x4 of[4];
#pragma unroll
  for (int i = 0; i < 4; i++) of[i] = (f32x4){0.f, 0.f, 0.f, 0.f};
  float mrow[4] = {-1e30f, -1e30f, -1e30f, -1e30f};
  float lrow[4] = {0.f, 0.f, 0.f, 0.f};

  const int khi = qb + 15;
  short* myP = P_lds[w];

  for (int kb = 0; kb <= khi; kb += 64) {
    f32x4 sf[4];
#pragma unroll
    for (int f = 0; f < 4; f++) sf[f] = (f32x4){0.f, 0.f, 0.f, 0.f};
#pragma unroll
    for (int f = 0; f < 4; f++) {
      const float* kr = &Kb[(size_t)(kb + f * 16 + l16) * HDIM + lg * 8];
      f32x4 k00 = *(const f32x4*)kr;
      f32x4 k01 = *(const f32x4*)(kr + 4);
      f32x4 k10 = *(const f32x4*)(kr + 32);
      f32x4 k11 = *(const f32x4*)(kr + 36);
      s16x8 bk0, bk1;
#pragma unroll
      for (int j = 0; j < 4; j++) {
        bk0[j] = f2bf(k00[j]); bk0[4 + j] = f2bf(k01[j]);
        bk1[j] = f2bf(k10[j]); bk1[4 + j] = f2bf(k11[j]);
      }
      sf[f] = mfma16(aq0, bk0, sf[f]);
      sf[f] = mfma16(aq1, bk1, sf[f]);
    }
    // scale + causal mask
#pragma unroll
    for (int f = 0; f < 4; f++) {
      int key = kb + f * 16 + l16;
#pragma unroll
      for (int r = 0; r < 4; r++) {
        int q = qb + lg * 4 + r;
        float s = sf[f][r] * 0.125f;
        sf[f][r] = (key <= q) ? s : -1e30f;
      }
    }
    // online softmax over key dim (16 lanes of l16 x 4 frags)
    float pm[4];
#pragma unroll
    for (int r = 0; r < 4; r++)
      pm[r] = fmaxf(fmaxf(sf[0][r], sf[1][r]), fmaxf(sf[2][r], sf[3][r]));
#pragma unroll
    for (int msk = 1; msk <= 8; msk <<= 1) {
#pragma unroll
      for (int r = 0; r < 4; r++) pm[r] = fmaxf(pm[r], __shfl_xor(pm[r], msk));
    }
    float alpha[4], rs[4];
#pragma unroll
    for (int r = 0; r < 4; r++) {
      float mn = fmaxf(mrow[r], pm[r]);
      alpha[r] = __expf(mrow[r] - mn);
      mrow[r] = mn;
      rs[r] = 0.f;
    }
#pragma unroll
    for (int f = 0; f < 4; f++) {
#pragma unroll
      for (int r = 0; r < 4; r++) {
        float p = __expf(sf[f][r] - mrow[r]);
        rs[r] += p;
        myP[(lg * 4 + r) * 72 + f * 16 + l16] = f2bf(p);
      }
    }
#pragma unroll
    for (int msk = 1; msk <= 8; msk <<= 1) {
#pragma unroll
      for (int r = 0; r < 4; r++) rs[r] += __shfl_xor(rs[r], msk);
    }
#pragma unroll
    for (int r = 0; r < 4; r++) lrow[r] = lrow[r] * alpha[r] + rs[r];
#pragma unroll
    for (int hf = 0; hf < 4; hf++) {
#pragma unroll
      for (int r = 0; r < 4; r++) of[hf][r] *= alpha[r];
    }
    // P (A-frag) from LDS, V^T (B-frag) from ws
    s16x8 pa0 = *(const s16x8*)&myP[l16 * 72 + lg * 8];
    s16x8 pa1 = *(const s16x8*)&myP[l16 * 72 + 32 + lg * 8];
#pragma unroll
    for (int hf = 0; hf < 4; hf++) {
      const short* vr = &Vb[(size_t)(hf * 16 + l16) * S_LEN + kb + lg * 8];
      s16x8 bv0 = *(const s16x8*)vr;
      s16x8 bv1 = *(const s16x8*)(vr + 32);
      of[hf] = mfma16(pa0, bv0, of[hf]);
      of[hf] = mfma16(pa1, bv1, of[hf]);
    }
  }

  const int b = bh >> 4, h = bh & 15;
#pragma unroll
  for (int r = 0; r < 4; r++) {
    float inv = 1.f / lrow[r];
    int q = qb + lg * 4 + r;
    size_t base = ((size_t)(b * S_LEN + q)) * DMODEL + h * HDIM;
#pragma unroll
    for (int hf = 0; hf < 4; hf++)
      AO[base + hf * 16 + l16] = f2bf(of[hf][r] * inv);
  }
}

extern "C" void kernel_launch(void* const* d_in, const int* in_sizes, int n_in,
                              void* d_out, int out_size, void* d_ws,
                              size_t ws_size, hipStream_t stream) {
  const float* x = (const float*)d_in[0];
  const float* w_qkv = (const float*)d_in[1];
  const float* b_qkv = (const float*)d_in[2];
  const float* w_proj = (const float*)d_in[3];
  const float* b_proj = (const float*)d_in[4];
  float* out = (float*)d_out;
  float* presentK = out + OUT_ELEMS;               // f32 [bh][S][64]
  float* presentV = presentK + HEAD_ELEMS;         // f32 [bh][S][64]

  short* ws = (short*)d_ws;
  short* Qw = ws;                 // bf16 [bh][S][64]      4,194,304
  short* Vt = ws + 4194304;       // bf16 [bh][64][S]      4,194,304
  short* wprojT = ws + 8388608;   // bf16 [1024][1024]     1,048,576
  short* wqkvT = ws + 9437184;    // bf16 [3072][1024]     3,145,728
  short* attnout = ws + 9437184;  // bf16 [B][S][D] — overlays dead wqkvT

  if (ws_size < (size_t)27262976) return;  // 13,631,488 bf16 elems

  // weight convert+transpose
  transpose_cvt<<<dim3(1536, 1), 256, 0, stream>>>(w_qkv, wqkvT, 1024, 3072);
  transpose_cvt<<<dim3(512, 1), 256, 0, stream>>>(w_proj, wprojT, 1024, 1024);
  // QKV projection: Q -> ws (bf16), K/V -> present (f32)
  gemm_bt<0, true><<<dim3(24, 32), 256, 0, stream>>>(
      x, wqkvT, b_qkv, Qw, presentK, 4096, 3072, 1024);
  // V^T per (b,h): f32 present-V -> bf16 Vt
  transpose_cvt<<<dim3(64, 32), 256, 0, stream>>>(presentV, Vt, 2048, 64);
  // causal attention
  attn_fwd<<<dim3(32, 32), 256, 0, stream>>>(Qw, presentK, Vt, attnout);
  // output projection -> f32 out
  gemm_bt<1, false><<<dim3(8, 32), 256, 0, stream>>>(
      attnout, wprojT, b_proj, nullptr, out, 4096, 1024, 1024);
}

// Round 3
// 262.265 us; speedup vs baseline: 1.1682x; 1.1682x over previous
//
#include <hip/hip_runtime.h>
#include <hip/hip_bf16.h>

typedef short s16x8 __attribute__((ext_vector_type(8)));
typedef short s16x4 __attribute__((ext_vector_type(4)));
typedef float f32x4 __attribute__((ext_vector_type(4)));
typedef float f32x16 __attribute__((ext_vector_type(16)));
typedef unsigned int u32x4 __attribute__((ext_vector_type(4)));

#define S_LEN 2048
#define DMODEL 1024
#define NHEAD 16
#define HDIM 64
#define OUT_ELEMS 4194304   // B*S*D
#define HEAD_ELEMS 4194304  // B*H*S*HD
#define SCALE_LOG2 0.1803368801111204f  // 0.125 * log2(e)

__device__ inline short f2bf(float f) {
  __hip_bfloat16 h = __float2bfloat16(f);  // RNE
  return __builtin_bit_cast(short, h);
}

__device__ inline f32x4 mfma16(s16x8 a, s16x8 b, f32x4 c) {
  return __builtin_amdgcn_mfma_f32_16x16x32_bf16(a, b, c, 0, 0, 0);
}
__device__ inline f32x16 mfma32(s16x8 a, s16x8 b, f32x16 c) {
  return __builtin_amdgcn_mfma_f32_32x32x16_bf16(a, b, c, 0, 0, 0);
}

// ---- convert+transpose: in [R][C] f32 -> out [C][R] bf16 ----
__global__ __launch_bounds__(256) void transpose_cvt(
    const float* __restrict__ in, short* __restrict__ out, int R, int C) {
  int g = blockIdx.x * 256 + threadIdx.x;
  int c = g % C;
  int r0 = (g / C) * 8;
  s16x8 v;
#pragma unroll
  for (int j = 0; j < 8; j++) v[j] = f2bf(in[(size_t)(r0 + j) * C + c]);
  *(s16x8*)&out[(size_t)c * R + r0] = v;
}

// ---- GEMM: C = A[M,K] * Bt[N,K]^T + bias. ----
// MODE 0: QKV scatter: Q->Ob0 bf16, K->Of f32, V->Of f32 + VtOut bf16 (transposed)
// MODE 1: plain f32 row-major store to Of
template <int MODE, bool AF32>
__global__ __launch_bounds__(256) void gemm_bt(
    const void* __restrict__ Araw, const short* __restrict__ Bt,
    const float* __restrict__ bias, short* __restrict__ Ob0,
    float* __restrict__ Of, short* __restrict__ VtOut, int M, int N, int K) {
  __shared__ short As[128][40];
  __shared__ short Bs[128][40];
  const int t = threadIdx.x;
  const int lane = t & 63;
  const int wid = t >> 6;
  const int wr = wid >> 1, wc = wid & 1;
  const int l16 = lane & 15, lg = lane >> 4;
  const int mbase = blockIdx.y * 128;
  const int nbase = blockIdx.x * 128;

  f32x4 acc[4][4];
#pragma unroll
  for (int m = 0; m < 4; m++)
#pragma unroll
    for (int n = 0; n < 4; n++) acc[m][n] = (f32x4){0.f, 0.f, 0.f, 0.f};

  const int srow = t >> 2;
  const int skc = (t & 3) * 8;

  for (int k0 = 0; k0 < K; k0 += 32) {
    s16x8 a0, a1;
    if constexpr (AF32) {
      const float* Af = (const float*)Araw;
      const float* p0 = &Af[(size_t)(mbase + srow) * K + k0 + skc];
      const float* p1 = &Af[(size_t)(mbase + srow + 64) * K + k0 + skc];
      f32x4 x00 = *(const f32x4*)p0, x01 = *(const f32x4*)(p0 + 4);
      f32x4 x10 = *(const f32x4*)p1, x11 = *(const f32x4*)(p1 + 4);
#pragma unroll
      for (int j = 0; j < 4; j++) {
        a0[j] = f2bf(x00[j]); a0[4 + j] = f2bf(x01[j]);
        a1[j] = f2bf(x10[j]); a1[4 + j] = f2bf(x11[j]);
      }
    } else {
      const short* Ab = (const short*)Araw;
      a0 = *(const s16x8*)&Ab[(size_t)(mbase + srow) * K + k0 + skc];
      a1 = *(const s16x8*)&Ab[(size_t)(mbase + srow + 64) * K + k0 + skc];
    }
    s16x8 b0 = *(const s16x8*)&Bt[(size_t)(nbase + srow) * K + k0 + skc];
    s16x8 b1 = *(const s16x8*)&Bt[(size_t)(nbase + srow + 64) * K + k0 + skc];
    __syncthreads();
    *(s16x8*)&As[srow][skc] = a0;
    *(s16x8*)&As[srow + 64][skc] = a1;
    *(s16x8*)&Bs[srow][skc] = b0;
    *(s16x8*)&Bs[srow + 64][skc] = b1;
    __syncthreads();
    s16x8 af[4], bfr[4];
#pragma unroll
    for (int m = 0; m < 4; m++)
      af[m] = *(const s16x8*)&As[wr * 64 + m * 16 + l16][lg * 8];
#pragma unroll
    for (int n = 0; n < 4; n++)
      bfr[n] = *(const s16x8*)&Bs[wc * 64 + n * 16 + l16][lg * 8];
#pragma unroll
    for (int m = 0; m < 4; m++)
#pragma unroll
      for (int n = 0; n < 4; n++)
        acc[m][n] = mfma16(af[m], bfr[n], acc[m][n]);
  }

#pragma unroll
  for (int m = 0; m < 4; m++) {
#pragma unroll
    for (int n = 0; n < 4; n++) {
      int gcol = nbase + wc * 64 + n * 16 + l16;
      float bv = bias[gcol];
      int part = gcol >> 10;
      int cin = gcol & 1023;
      int h = cin >> 6, hd = cin & 63;
      int grow0 = mbase + wr * 64 + m * 16 + lg * 4;
      float vr[4];
#pragma unroll
      for (int r = 0; r < 4; r++) vr[r] = acc[m][n][r] + bv;
      if (MODE == 0) {
        int bb = grow0 >> 11, s0 = grow0 & 2047;
        size_t base = ((size_t)(bb * NHEAD + h) * S_LEN + s0) * HDIM + hd;
        if (part == 0) {
#pragma unroll
          for (int r = 0; r < 4; r++) Ob0[base + (size_t)r * HDIM] = f2bf(vr[r]);
        } else if (part == 1) {
#pragma unroll
          for (int r = 0; r < 4; r++) Of[base + (size_t)r * HDIM] = vr[r];
        } else {
#pragma unroll
          for (int r = 0; r < 4; r++)
            Of[HEAD_ELEMS + base + (size_t)r * HDIM] = vr[r];
          s16x4 pk;
#pragma unroll
          for (int r = 0; r < 4; r++) pk[r] = f2bf(vr[r]);
          *(s16x4*)&VtOut[((size_t)(bb * NHEAD + h) * HDIM + hd) * S_LEN + s0] = pk;
        }
      } else {
#pragma unroll
        for (int r = 0; r < 4; r++) Of[(size_t)(grow0 + r) * N + gcol] = vr[r];
      }
    }
  }
}

// ---- causal flash attention, swapped-operand 32x32 MFMA, no LDS ----------
// Q: bf16 [bh][S][64], Kf: f32 [bh][S][64] (present-k), Vt: bf16 [bh][64][S]
// AO: bf16 [B][S][D]
__global__ __launch_bounds__(256, 4) void attn_fwd32(
    const short* __restrict__ Q, const float* __restrict__ Kf,
    const short* __restrict__ Vt, short* __restrict__ AO) {
  // XCD swizzle: 1024 blocks, XCD x gets bh in {x, x+8, x+16, x+24}
  int p = blockIdx.x + (blockIdx.y << 5);
  int xcd = p & 7, slot = p >> 3;
  int bh = xcd + 8 * (slot >> 5);
  int kblk = slot & 31;
  const int w = threadIdx.x >> 6;
  // balanced jobs: trips (2k+1)+(2k+2)+(64-2k)+(63-2k) = 130 per block
  int j = (w == 0) ? 2 * kblk
        : (w == 1) ? 2 * kblk + 1
        : (w == 2) ? 63 - 2 * kblk
                   : 62 - 2 * kblk;
  const int lane = threadIdx.x & 63;
  const int l32 = lane & 31;
  const int hi = lane >> 5;
  const int qb = j * 32;

  const short* Qb = Q + (size_t)bh * (S_LEN * HDIM);
  const float* Kb = Kf + (size_t)bh * (S_LEN * HDIM);
  const short* Vb = Vt + (size_t)bh * (HDIM * S_LEN);

  // Q as B-operand: col q = l32, k-elems = c*16 + hi*8 + j
  s16x8 qf[4];
#pragma unroll
  for (int c = 0; c < 4; c++)
    qf[c] = *(const s16x8*)&Qb[(size_t)(qb + l32) * HDIM + c * 16 + hi * 8];

  f32x16 acc0 = {0.f}, acc1 = {0.f};
  float m = -1e30f, ll = 0.f;

  for (int kb = 0; kb <= qb; kb += 32) {
    // S^T[key][q] = K . Q^T  (A = K-tile rows=keys, B = Q cols=q)
    f32x16 S = {0.f};
#pragma unroll
    for (int c = 0; c < 4; c++) {
      const float* kr = &Kb[(size_t)(kb + l32) * HDIM + c * 16 + hi * 8];
      f32x4 k0 = *(const f32x4*)kr, k1 = *(const f32x4*)(kr + 4);
      s16x8 kfrag;
#pragma unroll
      for (int u = 0; u < 4; u++) {
        kfrag[u] = f2bf(k0[u]);
        kfrag[4 + u] = f2bf(k1[u]);
      }
      S = mfma32(kfrag, qf[c], S);
    }
    // scale (+ causal mask on diagonal tile); tile max
    float tmax = -1e30f;
    if (kb == qb) {
#pragma unroll
      for (int r = 0; r < 16; r++) {
        int keyl = (r & 3) + 8 * (r >> 2) + 4 * hi;
        float v = S[r] * SCALE_LOG2;
        v = (keyl <= l32) ? v : -1e30f;
        S[r] = v;
        tmax = fmaxf(tmax, v);
      }
    } else {
#pragma unroll
      for (int r = 0; r < 16; r++) {
        S[r] *= SCALE_LOG2;
        tmax = fmaxf(tmax, S[r]);
      }
    }
    tmax = fmaxf(tmax, __shfl_xor(tmax, 32));
    // defer-max: only rescale when tile max grew past THR (log2 units)
    if (!__all(tmax <= m + 11.0f)) {
      float mn = fmaxf(m, tmax);
      float alpha = exp2f(m - mn);
      ll *= alpha;
#pragma unroll
      for (int r = 0; r < 16; r++) {
        acc0[r] *= alpha;
        acc1[r] *= alpha;
      }
      m = mn;
    }
    float rs = 0.f;
#pragma unroll
    for (int r = 0; r < 16; r++) {
      float pv = exp2f(S[r] - m);
      S[r] = pv;
      rs += pv;
    }
    rs += __shfl_xor(rs, 32);
    ll += rs;
    // pack P to bf16 pairs: W[2g+t] = (p[4g+2t], p[4g+2t+1])
    unsigned int W[8];
#pragma unroll
    for (int g = 0; g < 4; g++) {
#pragma unroll
      for (int u = 0; u < 2; u++) {
        unsigned int lo = (unsigned short)f2bf(S[4 * g + 2 * u]);
        unsigned int hi16 = (unsigned short)f2bf(S[4 * g + 2 * u + 1]);
        W[2 * g + u] = lo | (hi16 << 16);
      }
    }
    // PV: O^T[d][q] += V^T . P^T, two 16-key chunks, two d-tiles
#pragma unroll
    for (int kc = 0; kc < 2; kc++) {
      unsigned int s0 = hi ? W[4 * kc] : W[4 * kc + 2];
      unsigned int s1 = hi ? W[4 * kc + 1] : W[4 * kc + 3];
      unsigned int r0 = (unsigned int)__shfl_xor((int)s0, 32);
      unsigned int r1 = (unsigned int)__shfl_xor((int)s1, 32);
      u32x4 bw;
      if (hi) {
        bw[0] = r0; bw[1] = r1; bw[2] = W[4 * kc + 2]; bw[3] = W[4 * kc + 3];
      } else {
        bw[0] = W[4 * kc]; bw[1] = W[4 * kc + 1]; bw[2] = r0; bw[3] = r1;
      }
      s16x8 pb = __builtin_bit_cast(s16x8, bw);
      s16x8 va0 = *(const s16x8*)&Vb[(size_t)l32 * S_LEN + kb + kc * 16 + hi * 8];
      s16x8 va1 =
          *(const s16x8*)&Vb[(size_t)(32 + l32) * S_LEN + kb + kc * 16 + hi * 8];
      acc0 = mfma32(va0, pb, acc0);
      acc1 = mfma32(va1, pb, acc1);
    }
  }

  float inv = 1.f / ll;
  const int b = bh >> 4, h = bh & 15;
  size_t rowbase = ((size_t)(b * S_LEN + qb + l32)) * DMODEL + h * HDIM;
#pragma unroll
  for (int g = 0; g < 4; g++) {
    s16x4 o0, o1;
#pragma unroll
    for (int u = 0; u < 4; u++) {
      o0[u] = f2bf(acc0[4 * g + u] * inv);
      o1[u] = f2bf(acc1[4 * g + u] * inv);
    }
    *(s16x4*)&AO[rowbase + 8 * g + 4 * hi] = o0;
    *(s16x4*)&AO[rowbase + 32 + 8 * g + 4 * hi] = o1;
  }
}

extern "C" void kernel_launch(void* const* d_in, const int* in_sizes, int n_in,
                              void* d_out, int out_size, void* d_ws,
                              size_t ws_size, hipStream_t stream) {
  const float* x = (const float*)d_in[0];
  const float* w_qkv = (const float*)d_in[1];
  const float* b_qkv = (const float*)d_in[2];
  const float* w_proj = (const float*)d_in[3];
  const float* b_proj = (const float*)d_in[4];
  float* out = (float*)d_out;
  float* presentK = out + OUT_ELEMS;        // f32 [bh][S][64]

  short* ws = (short*)d_ws;
  short* Qw = ws;                  // bf16 [bh][S][64]   4,194,304
  short* Vt = ws + 4194304;        // bf16 [bh][64][S]   4,194,304
  short* wprojT = ws + 8388608;    // bf16 [1024][1024]  1,048,576
  short* wqkvT = ws + 9437184;     // bf16 [3072][1024]  3,145,728
  short* attnout = ws + 9437184;   // bf16 [B][S][D] — overlays dead wqkvT

  if (ws_size < (size_t)27262976) return;

  transpose_cvt<<<dim3(1536), 256, 0, stream>>>(w_qkv, wqkvT, 1024, 3072);
  transpose_cvt<<<dim3(512), 256, 0, stream>>>(w_proj, wprojT, 1024, 1024);
  // QKV projection: Q->Qw bf16, K->presentK f32, V->presentV f32 + Vt bf16
  gemm_bt<0, true><<<dim3(24, 32), 256, 0, stream>>>(
      x, wqkvT, b_qkv, Qw, presentK, Vt, 4096, 3072, 1024);
  // causal attention
  attn_fwd32<<<dim3(32, 32), 256, 0, stream>>>(Qw, presentK, Vt, attnout);
  // output projection -> f32 out
  gemm_bt<1, false><<<dim3(8, 32), 256, 0, stream>>>(
      attnout, wprojT, b_proj, nullptr, out, nullptr, 4096, 1024, 1024);
}

// Round 4
// 165.064 us; speedup vs baseline: 1.8561x; 1.5889x over previous
//
#include <hip/hip_runtime.h>
#include <hip/hip_bf16.h>

typedef short s16x8 __attribute__((ext_vector_type(8)));
typedef short s16x4 __attribute__((ext_vector_type(4)));
typedef float f32x4 __attribute__((ext_vector_type(4)));
typedef float f32x16 __attribute__((ext_vector_type(16)));
typedef unsigned int u32x4 __attribute__((ext_vector_type(4)));

#define S_LEN 2048
#define DMODEL 1024
#define NHEAD 16
#define HDIM 64
#define OUT_ELEMS 4194304   // B*S*D
#define HEAD_ELEMS 4194304  // B*H*S*HD
#define SCALE_LOG2 0.1803368801111204f  // 0.125 * log2(e), folded into Q

__device__ inline short f2bf(float f) {
  __hip_bfloat16 h = __float2bfloat16(f);  // RNE
  return __builtin_bit_cast(short, h);
}

__device__ inline f32x4 mfma16(s16x8 a, s16x8 b, f32x4 c) {
  return __builtin_amdgcn_mfma_f32_16x16x32_bf16(a, b, c, 0, 0, 0);
}
__device__ inline f32x16 mfma32(s16x8 a, s16x8 b, f32x16 c) {
  return __builtin_amdgcn_mfma_f32_32x32x16_bf16(a, b, c, 0, 0, 0);
}

// ---- convert+transpose: in [R][C] f32 -> out [C][R] bf16 ----
__global__ __launch_bounds__(256) void transpose_cvt(
    const float* __restrict__ in, short* __restrict__ out, int R, int C) {
  int g = blockIdx.x * 256 + threadIdx.x;
  int c = g % C;
  int r0 = (g / C) * 8;
  s16x8 v;
#pragma unroll
  for (int j = 0; j < 8; j++) v[j] = f2bf(in[(size_t)(r0 + j) * C + c]);
  *(s16x8*)&out[(size_t)c * R + r0] = v;
}

// ---- GEMM: C = A[M,K] * Bt[N,K]^T + bias. ----
// MODE 0: QKV scatter: Q(pre-scaled)->Ob0 bf16, K->Of f32 (+KwOut bf16),
//         V->Of f32 + VtOut bf16 (transposed)
// MODE 1: plain f32 row-major store to Of
template <int MODE, bool AF32>
__global__ __launch_bounds__(256) void gemm_bt(
    const void* __restrict__ Araw, const short* __restrict__ Bt,
    const float* __restrict__ bias, short* __restrict__ Ob0,
    float* __restrict__ Of, short* __restrict__ VtOut,
    short* __restrict__ KwOut, int M, int N, int K) {
  __shared__ short As[128][40];
  __shared__ short Bs[128][40];
  const int t = threadIdx.x;
  const int lane = t & 63;
  const int wid = t >> 6;
  const int wr = wid >> 1, wc = wid & 1;
  const int l16 = lane & 15, lg = lane >> 4;
  const int mbase = blockIdx.y * 128;
  const int nbase = blockIdx.x * 128;

  f32x4 acc[4][4];
#pragma unroll
  for (int m = 0; m < 4; m++)
#pragma unroll
    for (int n = 0; n < 4; n++) acc[m][n] = (f32x4){0.f, 0.f, 0.f, 0.f};

  const int srow = t >> 2;
  const int skc = (t & 3) * 8;

  for (int k0 = 0; k0 < K; k0 += 32) {
    s16x8 a0, a1;
    if constexpr (AF32) {
      const float* Af = (const float*)Araw;
      const float* p0 = &Af[(size_t)(mbase + srow) * K + k0 + skc];
      const float* p1 = &Af[(size_t)(mbase + srow + 64) * K + k0 + skc];
      f32x4 x00 = *(const f32x4*)p0, x01 = *(const f32x4*)(p0 + 4);
      f32x4 x10 = *(const f32x4*)p1, x11 = *(const f32x4*)(p1 + 4);
#pragma unroll
      for (int j = 0; j < 4; j++) {
        a0[j] = f2bf(x00[j]); a0[4 + j] = f2bf(x01[j]);
        a1[j] = f2bf(x10[j]); a1[4 + j] = f2bf(x11[j]);
      }
    } else {
      const short* Ab = (const short*)Araw;
      a0 = *(const s16x8*)&Ab[(size_t)(mbase + srow) * K + k0 + skc];
      a1 = *(const s16x8*)&Ab[(size_t)(mbase + srow + 64) * K + k0 + skc];
    }
    s16x8 b0 = *(const s16x8*)&Bt[(size_t)(nbase + srow) * K + k0 + skc];
    s16x8 b1 = *(const s16x8*)&Bt[(size_t)(nbase + srow + 64) * K + k0 + skc];
    __syncthreads();
    *(s16x8*)&As[srow][skc] = a0;
    *(s16x8*)&As[srow + 64][skc] = a1;
    *(s16x8*)&Bs[srow][skc] = b0;
    *(s16x8*)&Bs[srow + 64][skc] = b1;
    __syncthreads();
    s16x8 af[4], bfr[4];
#pragma unroll
    for (int m = 0; m < 4; m++)
      af[m] = *(const s16x8*)&As[wr * 64 + m * 16 + l16][lg * 8];
#pragma unroll
    for (int n = 0; n < 4; n++)
      bfr[n] = *(const s16x8*)&Bs[wc * 64 + n * 16 + l16][lg * 8];
#pragma unroll
    for (int m = 0; m < 4; m++)
#pragma unroll
      for (int n = 0; n < 4; n++)
        acc[m][n] = mfma16(af[m], bfr[n], acc[m][n]);
  }

#pragma unroll
  for (int m = 0; m < 4; m++) {
#pragma unroll
    for (int n = 0; n < 4; n++) {
      int gcol = nbase + wc * 64 + n * 16 + l16;
      float bv = bias[gcol];
      int part = gcol >> 10;
      int cin = gcol & 1023;
      int h = cin >> 6, hd = cin & 63;
      int grow0 = mbase + wr * 64 + m * 16 + lg * 4;
      float vr[4];
#pragma unroll
      for (int r = 0; r < 4; r++) vr[r] = acc[m][n][r] + bv;
      if (MODE == 0) {
        int bb = grow0 >> 11, s0 = grow0 & 2047;
        size_t base = ((size_t)(bb * NHEAD + h) * S_LEN + s0) * HDIM + hd;
        if (part == 0) {
#pragma unroll
          for (int r = 0; r < 4; r++)
            Ob0[base + (size_t)r * HDIM] = f2bf(vr[r] * SCALE_LOG2);
        } else if (part == 1) {
#pragma unroll
          for (int r = 0; r < 4; r++) Of[base + (size_t)r * HDIM] = vr[r];
          if (KwOut) {
#pragma unroll
            for (int r = 0; r < 4; r++)
              KwOut[base + (size_t)r * HDIM] = f2bf(vr[r]);
          }
        } else {
#pragma unroll
          for (int r = 0; r < 4; r++)
            Of[HEAD_ELEMS + base + (size_t)r * HDIM] = vr[r];
          s16x4 pk;
#pragma unroll
          for (int r = 0; r < 4; r++) pk[r] = f2bf(vr[r]);
          *(s16x4*)&VtOut[((size_t)(bb * NHEAD + h) * HDIM + hd) * S_LEN + s0] = pk;
        }
      } else {
#pragma unroll
        for (int r = 0; r < 4; r++) Of[(size_t)(grow0 + r) * N + gcol] = vr[r];
      }
    }
  }
}

// ---- causal flash attention: k-split across 4 waves + LDS combine --------
// Q: bf16 [bh][S][64] pre-scaled by 0.125*log2e; K: bf16 or f32 [bh][S][64];
// Vt: bf16 [bh][64][S]; AO: bf16 [B][S][D]
template <bool KBF16>
__global__ __launch_bounds__(256, 4) void attn_fwd_ks(
    const short* __restrict__ Q, const void* __restrict__ Kraw,
    const short* __restrict__ Vt, short* __restrict__ AO) {
  __shared__ float XFER[2][64][37];

  const int p = blockIdx.x;          // 2048 blocks
  const int xcd = p & 7;
  const int rank = p >> 3;           // 0..255
  const int bh = (xcd << 2) | (rank >> 6);  // 4 bh per dispatch-residue class
  const int j = 63 - (rank & 63);    // big jobs first
  const int qb = j * 32;

  const int tid = threadIdx.x;
  const int w = tid >> 6;
  const int lane = tid & 63;
  const int l32 = lane & 31;
  const int hi = lane >> 5;

  const short* Qb = Q + (size_t)bh * (S_LEN * HDIM);
  const short* Vb = Vt + (size_t)bh * (HDIM * S_LEN);

  // Q as B-operand: col q = l32, k-elems = c*16 + hi*8 + u
  s16x8 qf[4];
#pragma unroll
  for (int c = 0; c < 4; c++)
    qf[c] = *(const s16x8*)&Qb[(size_t)(qb + l32) * HDIM + c * 16 + hi * 8];

  f32x16 acc0 = {0.f}, acc1 = {0.f};
  float m = -1e30f, ll = 0.f;

  for (int kt = w; kt <= j; kt += 4) {
    const int kb = kt * 32;
    // S^T[key][q] = K . Q^T
    f32x16 S = {0.f};
#pragma unroll
    for (int c = 0; c < 4; c++) {
      s16x8 kfrag;
      if constexpr (KBF16) {
        const short* Kb = (const short*)Kraw + (size_t)bh * (S_LEN * HDIM);
        kfrag = *(const s16x8*)&Kb[(size_t)(kb + l32) * HDIM + c * 16 + hi * 8];
      } else {
        const float* Kb = (const float*)Kraw + (size_t)bh * (S_LEN * HDIM);
        const float* kr = &Kb[(size_t)(kb + l32) * HDIM + c * 16 + hi * 8];
        f32x4 k0 = *(const f32x4*)kr, k1 = *(const f32x4*)(kr + 4);
#pragma unroll
        for (int u = 0; u < 4; u++) {
          kfrag[u] = f2bf(k0[u]);
          kfrag[4 + u] = f2bf(k1[u]);
        }
      }
      S = mfma32(kfrag, qf[c], S);
    }
    // causal mask on diagonal tile (Q pre-scaled; S already in log2 domain)
    float tmax = -1e30f;
    if (kt == j) {
#pragma unroll
      for (int r = 0; r < 16; r++) {
        int keyl = (r & 3) + 8 * (r >> 2) + 4 * hi;
        float v = (keyl <= l32) ? S[r] : -1e30f;
        S[r] = v;
        tmax = fmaxf(tmax, v);
      }
    } else {
#pragma unroll
      for (int r = 0; r < 16; r++) tmax = fmaxf(tmax, S[r]);
    }
    tmax = fmaxf(tmax, __shfl_xor(tmax, 32));
    // defer-max: rescale only when tile max grows past threshold
    if (!__all(tmax <= m + 11.0f)) {
      float mn = fmaxf(m, tmax);
      float alpha = exp2f(m - mn);
      ll *= alpha;
#pragma unroll
      for (int r = 0; r < 16; r++) {
        acc0[r] *= alpha;
        acc1[r] *= alpha;
      }
      m = mn;
    }
    float rs = 0.f;
#pragma unroll
    for (int r = 0; r < 16; r++) {
      float pv = exp2f(S[r] - m);
      S[r] = pv;
      rs += pv;
    }
    rs += __shfl_xor(rs, 32);
    ll += rs;
    // pack P to bf16 pairs
    unsigned int W[8];
#pragma unroll
    for (int g = 0; g < 4; g++) {
#pragma unroll
      for (int u = 0; u < 2; u++) {
        unsigned int lo = (unsigned short)f2bf(S[4 * g + 2 * u]);
        unsigned int hi16 = (unsigned short)f2bf(S[4 * g + 2 * u + 1]);
        W[2 * g + u] = lo | (hi16 << 16);
      }
    }
    // PV: O^T[d][q] += V^T . P^T
#pragma unroll
    for (int kc = 0; kc < 2; kc++) {
      unsigned int s0 = hi ? W[4 * kc] : W[4 * kc + 2];
      unsigned int s1 = hi ? W[4 * kc + 1] : W[4 * kc + 3];
      unsigned int r0 = (unsigned int)__shfl_xor((int)s0, 32);
      unsigned int r1 = (unsigned int)__shfl_xor((int)s1, 32);
      u32x4 bw;
      if (hi) {
        bw[0] = r0; bw[1] = r1; bw[2] = W[4 * kc + 2]; bw[3] = W[4 * kc + 3];
      } else {
        bw[0] = W[4 * kc]; bw[1] = W[4 * kc + 1]; bw[2] = r0; bw[3] = r1;
      }
      s16x8 pb = __builtin_bit_cast(s16x8, bw);
      s16x8 va0 = *(const s16x8*)&Vb[(size_t)l32 * S_LEN + kb + kc * 16 + hi * 8];
      s16x8 va1 =
          *(const s16x8*)&Vb[(size_t)(32 + l32) * S_LEN + kb + kc * 16 + hi * 8];
      acc0 = mfma32(va0, pb, acc0);
      acc1 = mfma32(va1, pb, acc1);
    }
  }

  // ---- combine the 4 per-wave partials (tree merge via LDS) ----
  // publish: m,l,acc -> XFER[slot]; merge: fold XFER[slot] into local state
  if (w & 1) {  // waves 1,3 -> slots 0,1
    float* dst = &XFER[w >> 1][lane][0];
    dst[0] = m; dst[1] = ll;
#pragma unroll
    for (int r = 0; r < 16; r++) { dst[2 + r] = acc0[r]; dst[18 + r] = acc1[r]; }
  }
  __syncthreads();
  if (!(w & 1)) {  // waves 0,2 fold slots 0,1
    const float* src = &XFER[w >> 1][lane][0];
    float m2 = src[0], l2 = src[1];
    float M = fmaxf(m, m2);
    float a1 = exp2f(m - M), a2 = exp2f(m2 - M);
    ll = ll * a1 + l2 * a2;
#pragma unroll
    for (int r = 0; r < 16; r++) {
      acc0[r] = acc0[r] * a1 + src[2 + r] * a2;
      acc1[r] = acc1[r] * a1 + src[18 + r] * a2;
    }
    m = M;
  }
  __syncthreads();
  if (w == 2) {
    float* dst = &XFER[0][lane][0];
    dst[0] = m; dst[1] = ll;
#pragma unroll
    for (int r = 0; r < 16; r++) { dst[2 + r] = acc0[r]; dst[18 + r] = acc1[r]; }
  }
  __syncthreads();
  if (w == 0) {
    const float* src = &XFER[0][lane][0];
    float m2 = src[0], l2 = src[1];
    float M = fmaxf(m, m2);
    float a1 = exp2f(m - M), a2 = exp2f(m2 - M);
    ll = ll * a1 + l2 * a2;
#pragma unroll
    for (int r = 0; r < 16; r++) {
      acc0[r] = acc0[r] * a1 + src[2 + r] * a2;
      acc1[r] = acc1[r] * a1 + src[18 + r] * a2;
    }
    float inv = 1.f / ll;
    const int b = bh >> 4, h = bh & 15;
    size_t rowbase = ((size_t)(b * S_LEN + qb + l32)) * DMODEL + h * HDIM;
#pragma unroll
    for (int g = 0; g < 4; g++) {
      s16x4 o0, o1;
#pragma unroll
      for (int u = 0; u < 4; u++) {
        o0[u] = f2bf(acc0[4 * g + u] * inv);
        o1[u] = f2bf(acc1[4 * g + u] * inv);
      }
      *(s16x4*)&AO[rowbase + 8 * g + 4 * hi] = o0;
      *(s16x4*)&AO[rowbase + 32 + 8 * g + 4 * hi] = o1;
    }
  }
}

extern "C" void kernel_launch(void* const* d_in, const int* in_sizes, int n_in,
                              void* d_out, int out_size, void* d_ws,
                              size_t ws_size, hipStream_t stream) {
  const float* x = (const float*)d_in[0];
  const float* w_qkv = (const float*)d_in[1];
  const float* b_qkv = (const float*)d_in[2];
  const float* w_proj = (const float*)d_in[3];
  const float* b_proj = (const float*)d_in[4];
  float* out = (float*)d_out;
  float* presentK = out + OUT_ELEMS;  // f32 [bh][S][64]

  short* ws = (short*)d_ws;
  const bool kbf16 = ws_size >= (size_t)35651584;  // 17,825,792 shorts

  short *Qw, *Vt, *wprojT, *wqkvT, *attnout, *Kw;
  if (kbf16) {
    Qw = ws;                  // 4,194,304
    Kw = ws + 4194304;        // 4,194,304
    Vt = ws + 8388608;        // 4,194,304
    wprojT = ws + 12582912;   // 1,048,576
    wqkvT = ws + 13631488;    // 3,145,728 (dead after QKV gemm)
    attnout = ws + 13631488;  // 4,194,304 (overlays wqkvT)
  } else {
    if (ws_size < (size_t)27262976) return;
    Qw = ws;
    Vt = ws + 4194304;
    wprojT = ws + 8388608;
    wqkvT = ws + 9437184;
    attnout = ws + 9437184;
    Kw = nullptr;
  }

  transpose_cvt<<<dim3(1536), 256, 0, stream>>>(w_qkv, wqkvT, 1024, 3072);
  transpose_cvt<<<dim3(512), 256, 0, stream>>>(w_proj, wprojT, 1024, 1024);
  // QKV projection: Q(pre-scaled)->Qw, K->presentK f32 (+Kw bf16), V->f32+Vt
  gemm_bt<0, true><<<dim3(24, 32), 256, 0, stream>>>(
      x, wqkvT, b_qkv, Qw, presentK, Vt, Kw, 4096, 3072, 1024);
  // causal attention (k-split + combine)
  if (kbf16)
    attn_fwd_ks<true><<<dim3(2048), 256, 0, stream>>>(Qw, Kw, Vt, attnout);
  else
    attn_fwd_ks<false><<<dim3(2048), 256, 0, stream>>>(Qw, presentK, Vt,
                                                       attnout);
  // output projection -> f32 out
  gemm_bt<1, false><<<dim3(8, 32), 256, 0, stream>>>(
      attnout, wprojT, b_proj, nullptr, out, nullptr, nullptr, 4096, 1024,
      1024);
}

// Round 5
// 154.931 us; speedup vs baseline: 1.9775x; 1.0654x over previous
//
#include <hip/hip_runtime.h>
#include <hip/hip_bf16.h>

typedef short s16x8 __attribute__((ext_vector_type(8)));
typedef short s16x4 __attribute__((ext_vector_type(4)));
typedef float f32x4 __attribute__((ext_vector_type(4)));
typedef float f32x16 __attribute__((ext_vector_type(16)));
typedef unsigned int u32x4 __attribute__((ext_vector_type(4)));

#define S_LEN 2048
#define DMODEL 1024
#define NHEAD 16
#define HDIM 64
#define OUT_ELEMS 4194304   // B*S*D
#define HEAD_ELEMS 4194304  // B*H*S*HD
#define SCALE_LOG2 0.1803368801111204f  // 0.125 * log2(e), folded into Q

__device__ inline short f2bf(float f) {
  __hip_bfloat16 h = __float2bfloat16(f);  // RNE
  return __builtin_bit_cast(short, h);
}

__device__ inline f32x4 mfma16(s16x8 a, s16x8 b, f32x4 c) {
  return __builtin_amdgcn_mfma_f32_16x16x32_bf16(a, b, c, 0, 0, 0);
}
__device__ inline f32x16 mfma32(s16x8 a, s16x8 b, f32x16 c) {
  return __builtin_amdgcn_mfma_f32_32x32x16_bf16(a, b, c, 0, 0, 0);
}

// ---- convert+transpose: in [R][C] f32 -> out [C][R] bf16 ----
__global__ __launch_bounds__(256) void transpose_cvt(
    const float* __restrict__ in, short* __restrict__ out, int R, int C) {
  int g = blockIdx.x * 256 + threadIdx.x;
  int c = g % C;
  int r0 = (g / C) * 8;
  s16x8 v;
#pragma unroll
  for (int j = 0; j < 8; j++) v[j] = f2bf(in[(size_t)(r0 + j) * C + c]);
  *(s16x8*)&out[(size_t)c * R + r0] = v;
}

// ---- GEMM: C = A[M,K] * Bt[N,K]^T + bias. ----
template <int MODE, bool AF32>
__global__ __launch_bounds__(256) void gemm_bt(
    const void* __restrict__ Araw, const short* __restrict__ Bt,
    const float* __restrict__ bias, short* __restrict__ Ob0,
    float* __restrict__ Of, short* __restrict__ VtOut,
    short* __restrict__ KwOut, int M, int N, int K) {
  __shared__ short As[128][40];
  __shared__ short Bs[128][40];
  const int t = threadIdx.x;
  const int lane = t & 63;
  const int wid = t >> 6;
  const int wr = wid >> 1, wc = wid & 1;
  const int l16 = lane & 15, lg = lane >> 4;
  const int mbase = blockIdx.y * 128;
  const int nbase = blockIdx.x * 128;

  f32x4 acc[4][4];
#pragma unroll
  for (int m = 0; m < 4; m++)
#pragma unroll
    for (int n = 0; n < 4; n++) acc[m][n] = (f32x4){0.f, 0.f, 0.f, 0.f};

  const int srow = t >> 2;
  const int skc = (t & 3) * 8;

  for (int k0 = 0; k0 < K; k0 += 32) {
    s16x8 a0, a1;
    if constexpr (AF32) {
      const float* Af = (const float*)Araw;
      const float* p0 = &Af[(size_t)(mbase + srow) * K + k0 + skc];
      const float* p1 = &Af[(size_t)(mbase + srow + 64) * K + k0 + skc];
      f32x4 x00 = *(const f32x4*)p0, x01 = *(const f32x4*)(p0 + 4);
      f32x4 x10 = *(const f32x4*)p1, x11 = *(const f32x4*)(p1 + 4);
#pragma unroll
      for (int j = 0; j < 4; j++) {
        a0[j] = f2bf(x00[j]); a0[4 + j] = f2bf(x01[j]);
        a1[j] = f2bf(x10[j]); a1[4 + j] = f2bf(x11[j]);
      }
    } else {
      const short* Ab = (const short*)Araw;
      a0 = *(const s16x8*)&Ab[(size_t)(mbase + srow) * K + k0 + skc];
      a1 = *(const s16x8*)&Ab[(size_t)(mbase + srow + 64) * K + k0 + skc];
    }
    s16x8 b0 = *(const s16x8*)&Bt[(size_t)(nbase + srow) * K + k0 + skc];
    s16x8 b1 = *(const s16x8*)&Bt[(size_t)(nbase + srow + 64) * K + k0 + skc];
    __syncthreads();
    *(s16x8*)&As[srow][skc] = a0;
    *(s16x8*)&As[srow + 64][skc] = a1;
    *(s16x8*)&Bs[srow][skc] = b0;
    *(s16x8*)&Bs[srow + 64][skc] = b1;
    __syncthreads();
    s16x8 af[4], bfr[4];
#pragma unroll
    for (int m = 0; m < 4; m++)
      af[m] = *(const s16x8*)&As[wr * 64 + m * 16 + l16][lg * 8];
#pragma unroll
    for (int n = 0; n < 4; n++)
      bfr[n] = *(const s16x8*)&Bs[wc * 64 + n * 16 + l16][lg * 8];
#pragma unroll
    for (int m = 0; m < 4; m++)
#pragma unroll
      for (int n = 0; n < 4; n++)
        acc[m][n] = mfma16(af[m], bfr[n], acc[m][n]);
  }

#pragma unroll
  for (int m = 0; m < 4; m++) {
#pragma unroll
    for (int n = 0; n < 4; n++) {
      int gcol = nbase + wc * 64 + n * 16 + l16;
      float bv = bias[gcol];
      int part = gcol >> 10;
      int cin = gcol & 1023;
      int h = cin >> 6, hd = cin & 63;
      int grow0 = mbase + wr * 64 + m * 16 + lg * 4;
      float vr[4];
#pragma unroll
      for (int r = 0; r < 4; r++) vr[r] = acc[m][n][r] + bv;
      if (MODE == 0) {
        int bb = grow0 >> 11, s0 = grow0 & 2047;
        size_t base = ((size_t)(bb * NHEAD + h) * S_LEN + s0) * HDIM + hd;
        if (part == 0) {
#pragma unroll
          for (int r = 0; r < 4; r++)
            Ob0[base + (size_t)r * HDIM] = f2bf(vr[r] * SCALE_LOG2);
        } else if (part == 1) {
#pragma unroll
          for (int r = 0; r < 4; r++) Of[base + (size_t)r * HDIM] = vr[r];
          if (KwOut) {
#pragma unroll
            for (int r = 0; r < 4; r++)
              KwOut[base + (size_t)r * HDIM] = f2bf(vr[r]);
          }
        } else {
#pragma unroll
          for (int r = 0; r < 4; r++)
            Of[HEAD_ELEMS + base + (size_t)r * HDIM] = vr[r];
          s16x4 pk;
#pragma unroll
          for (int r = 0; r < 4; r++) pk[r] = f2bf(vr[r]);
          *(s16x4*)&VtOut[((size_t)(bb * NHEAD + h) * HDIM + hd) * S_LEN + s0] = pk;
        }
      } else {
#pragma unroll
        for (int r = 0; r < 4; r++) Of[(size_t)(grow0 + r) * N + gcol] = vr[r];
      }
    }
  }
}

// ---- causal flash attention: paired q-tiles (j, 63-j) per block, ----------
// ---- k-split across 4 waves + LDS combine, K prefetch ---------------------
template <bool KBF16>
__device__ __forceinline__ void attn_body(const short* __restrict__ Q,
                                          const void* __restrict__ Kraw,
                                          const short* __restrict__ Vt,
                                          short* __restrict__ AO) {
  __shared__ float XFER[2][64][37];

  const int p = blockIdx.x;                 // 1024 blocks
  const int xcd = p & 7;
  const int rank = p >> 3;                  // 0..127
  const int bh = (xcd << 2) | (rank >> 5);  // 4 bh per XCD residue class
  const int pr = rank & 31;

  const int tid = threadIdx.x;
  const int w = tid >> 6;
  const int lane = tid & 63;
  const int l32 = lane & 31;
  const int hi = lane >> 5;

  const short* Qb = Q + (size_t)bh * (S_LEN * HDIM);
  const short* Vb = Vt + (size_t)bh * (HDIM * S_LEN);
  const short* Kb16 = (const short*)Kraw + (size_t)bh * (S_LEN * HDIM);
  const float* Kb32 = (const float*)Kraw + (size_t)bh * (S_LEN * HDIM);
  const int b = bh >> 4, h = bh & 15;

#pragma unroll 1
  for (int ph = 0; ph < 2; ph++) {
    const int j = ph ? pr : 63 - pr;   // pair sums to 65 trips -> equal CUs
    const int qb = j * 32;

    s16x8 qf[4];
#pragma unroll
    for (int c = 0; c < 4; c++)
      qf[c] = *(const s16x8*)&Qb[(size_t)(qb + l32) * HDIM + c * 16 + hi * 8];

    f32x16 acc0 = {0.f}, acc1 = {0.f};
    float m = -1e30f, ll = 0.f;

    s16x8 kcur[4];
    if constexpr (KBF16) {
      if (w <= j) {
#pragma unroll
        for (int c = 0; c < 4; c++)
          kcur[c] = *(const s16x8*)&Kb16[(size_t)(w * 32 + l32) * HDIM +
                                         c * 16 + hi * 8];
      }
    }

#pragma unroll 1
    for (int kt = w; kt <= j; kt += 4) {
      const int kb = kt * 32;
      // S^T[key][q] = K . Q^T
      f32x16 S = {0.f};
      if constexpr (KBF16) {
#pragma unroll
        for (int c = 0; c < 4; c++) S = mfma32(kcur[c], qf[c], S);
      } else {
#pragma unroll
        for (int c = 0; c < 4; c++) {
          const float* kr = &Kb32[(size_t)(kb + l32) * HDIM + c * 16 + hi * 8];
          f32x4 k0 = *(const f32x4*)kr, k1 = *(const f32x4*)(kr + 4);
          s16x8 kf;
#pragma unroll
          for (int u = 0; u < 4; u++) {
            kf[u] = f2bf(k0[u]);
            kf[4 + u] = f2bf(k1[u]);
          }
          S = mfma32(kf, qf[c], S);
        }
      }
      // V loads early (latency hides under softmax)
      s16x8 v00 = *(const s16x8*)&Vb[(size_t)l32 * S_LEN + kb + hi * 8];
      s16x8 v10 = *(const s16x8*)&Vb[(size_t)(32 + l32) * S_LEN + kb + hi * 8];
      s16x8 v01 = *(const s16x8*)&Vb[(size_t)l32 * S_LEN + kb + 16 + hi * 8];
      s16x8 v11 =
          *(const s16x8*)&Vb[(size_t)(32 + l32) * S_LEN + kb + 16 + hi * 8];
      // prefetch next K tile (hides under softmax+PV)
      if constexpr (KBF16) {
        if (kt + 4 <= j) {
#pragma unroll
          for (int c = 0; c < 4; c++)
            kcur[c] = *(const s16x8*)&Kb16[(size_t)(kb + 128 + l32) * HDIM +
                                           c * 16 + hi * 8];
        }
      }
      // causal mask on diagonal tile
      if (kt == j) {
#pragma unroll
        for (int r = 0; r < 16; r++) {
          int keyl = (r & 3) + 8 * (r >> 2) + 4 * hi;
          S[r] = (keyl <= l32) ? S[r] : -1e30f;
        }
      }
      // tile max (tree)
      float t8[8];
#pragma unroll
      for (int r = 0; r < 8; r++) t8[r] = fmaxf(S[2 * r], S[2 * r + 1]);
      float tmax = fmaxf(fmaxf(fmaxf(t8[0], t8[1]), fmaxf(t8[2], t8[3])),
                         fmaxf(fmaxf(t8[4], t8[5]), fmaxf(t8[6], t8[7])));
      tmax = fmaxf(tmax, __shfl_xor(tmax, 32));
      // defer-max rescale
      if (!__all(tmax <= m + 11.0f)) {
        float mn = fmaxf(m, tmax);
        float alpha = exp2f(m - mn);
        ll *= alpha;
#pragma unroll
        for (int r = 0; r < 16; r++) {
          acc0[r] *= alpha;
          acc1[r] *= alpha;
        }
        m = mn;
      }
#pragma unroll
      for (int r = 0; r < 16; r++) S[r] = exp2f(S[r] - m);
      // tile sum (tree)
      float s8[8];
#pragma unroll
      for (int r = 0; r < 8; r++) s8[r] = S[2 * r] + S[2 * r + 1];
      float rs = ((s8[0] + s8[1]) + (s8[2] + s8[3])) +
                 ((s8[4] + s8[5]) + (s8[6] + s8[7]));
      rs += __shfl_xor(rs, 32);
      ll += rs;
      // pack P to bf16 pairs
      unsigned int W[8];
#pragma unroll
      for (int g = 0; g < 4; g++) {
#pragma unroll
        for (int u = 0; u < 2; u++) {
          unsigned int lo = (unsigned short)f2bf(S[4 * g + 2 * u]);
          unsigned int h16 = (unsigned short)f2bf(S[4 * g + 2 * u + 1]);
          W[2 * g + u] = lo | (h16 << 16);
        }
      }
      // PV: O^T[d][q] += V^T . P^T
#pragma unroll
      for (int kc = 0; kc < 2; kc++) {
        unsigned int s0 = hi ? W[4 * kc] : W[4 * kc + 2];
        unsigned int s1 = hi ? W[4 * kc + 1] : W[4 * kc + 3];
        unsigned int r0 = (unsigned int)__shfl_xor((int)s0, 32);
        unsigned int r1 = (unsigned int)__shfl_xor((int)s1, 32);
        u32x4 bw;
        if (hi) {
          bw[0] = r0; bw[1] = r1; bw[2] = W[4 * kc + 2]; bw[3] = W[4 * kc + 3];
        } else {
          bw[0] = W[4 * kc]; bw[1] = W[4 * kc + 1]; bw[2] = r0; bw[3] = r1;
        }
        s16x8 pb = __builtin_bit_cast(s16x8, bw);
        if (kc == 0) {
          acc0 = mfma32(v00, pb, acc0);
          acc1 = mfma32(v10, pb, acc1);
        } else {
          acc0 = mfma32(v01, pb, acc0);
          acc1 = mfma32(v11, pb, acc1);
        }
      }
    }

    // ---- combine the 4 per-wave partials (tree merge via LDS) ----
    if (w & 1) {
      float* dst = &XFER[w >> 1][lane][0];
      dst[0] = m; dst[1] = ll;
#pragma unroll
      for (int r = 0; r < 16; r++) { dst[2 + r] = acc0[r]; dst[18 + r] = acc1[r]; }
    }
    __syncthreads();
    if (!(w & 1)) {
      const float* src = &XFER[w >> 1][lane][0];
      float m2 = src[0], l2 = src[1];
      float M = fmaxf(m, m2);
      float a1 = exp2f(m - M), a2 = exp2f(m2 - M);
      ll = ll * a1 + l2 * a2;
#pragma unroll
      for (int r = 0; r < 16; r++) {
        acc0[r] = acc0[r] * a1 + src[2 + r] * a2;
        acc1[r] = acc1[r] * a1 + src[18 + r] * a2;
      }
      m = M;
    }
    __syncthreads();
    if (w == 2) {
      float* dst = &XFER[0][lane][0];
      dst[0] = m; dst[1] = ll;
#pragma unroll
      for (int r = 0; r < 16; r++) { dst[2 + r] = acc0[r]; dst[18 + r] = acc1[r]; }
    }
    __syncthreads();
    if (w == 0) {
      const float* src = &XFER[0][lane][0];
      float m2 = src[0], l2 = src[1];
      float M = fmaxf(m, m2);
      float a1 = exp2f(m - M), a2 = exp2f(m2 - M);
      ll = ll * a1 + l2 * a2;
#pragma unroll
      for (int r = 0; r < 16; r++) {
        acc0[r] = acc0[r] * a1 + src[2 + r] * a2;
        acc1[r] = acc1[r] * a1 + src[18 + r] * a2;
      }
      float inv = 1.f / ll;
      size_t rowbase = ((size_t)(b * S_LEN + qb + l32)) * DMODEL + h * HDIM;
#pragma unroll
      for (int g = 0; g < 4; g++) {
        s16x4 o0, o1;
#pragma unroll
        for (int u = 0; u < 4; u++) {
          o0[u] = f2bf(acc0[4 * g + u] * inv);
          o1[u] = f2bf(acc1[4 * g + u] * inv);
        }
        *(s16x4*)&AO[rowbase + 8 * g + 4 * hi] = o0;
        *(s16x4*)&AO[rowbase + 32 + 8 * g + 4 * hi] = o1;
      }
    }
    __syncthreads();  // protect XFER reuse across phases
  }
}

__global__ __launch_bounds__(256, 4) void attn_fwd_kbf16(
    const short* __restrict__ Q, const short* __restrict__ K,
    const short* __restrict__ Vt, short* __restrict__ AO) {
  attn_body<true>(Q, K, Vt, AO);
}
__global__ __launch_bounds__(256, 4) void attn_fwd_kf32(
    const short* __restrict__ Q, const float* __restrict__ K,
    const short* __restrict__ Vt, short* __restrict__ AO) {
  attn_body<false>(Q, K, Vt, AO);
}

extern "C" void kernel_launch(void* const* d_in, const int* in_sizes, int n_in,
                              void* d_out, int out_size, void* d_ws,
                              size_t ws_size, hipStream_t stream) {
  const float* x = (const float*)d_in[0];
  const float* w_qkv = (const float*)d_in[1];
  const float* b_qkv = (const float*)d_in[2];
  const float* w_proj = (const float*)d_in[3];
  const float* b_proj = (const float*)d_in[4];
  float* out = (float*)d_out;
  float* presentK = out + OUT_ELEMS;  // f32 [bh][S][64]

  short* ws = (short*)d_ws;
  const bool kbf16 = ws_size >= (size_t)35651584;  // 17,825,792 shorts

  short *Qw, *Vt, *wprojT, *wqkvT, *attnout, *Kw;
  if (kbf16) {
    Qw = ws;                  // 4,194,304
    Kw = ws + 4194304;        // 4,194,304
    Vt = ws + 8388608;        // 4,194,304
    wprojT = ws + 12582912;   // 1,048,576
    wqkvT = ws + 13631488;    // 3,145,728 (dead after QKV gemm)
    attnout = ws + 13631488;  // 4,194,304 (overlays wqkvT)
  } else {
    if (ws_size < (size_t)27262976) return;
    Qw = ws;
    Vt = ws + 4194304;
    wprojT = ws + 8388608;
    wqkvT = ws + 9437184;
    attnout = ws + 9437184;
    Kw = nullptr;
  }

  transpose_cvt<<<dim3(1536), 256, 0, stream>>>(w_qkv, wqkvT, 1024, 3072);
  transpose_cvt<<<dim3(512), 256, 0, stream>>>(w_proj, wprojT, 1024, 1024);
  // QKV projection: Q(pre-scaled)->Qw, K->presentK f32 (+Kw bf16), V->f32+Vt
  gemm_bt<0, true><<<dim3(24, 32), 256, 0, stream>>>(
      x, wqkvT, b_qkv, Qw, presentK, Vt, Kw, 4096, 3072, 1024);
  // causal attention (paired q-tiles, k-split + combine)
  if (kbf16)
    attn_fwd_kbf16<<<dim3(1024), 256, 0, stream>>>(Qw, Kw, Vt, attnout);
  else
    attn_fwd_kf32<<<dim3(1024), 256, 0, stream>>>(Qw, presentK, Vt, attnout);
  // output projection -> f32 out
  gemm_bt<1, false><<<dim3(8, 32), 256, 0, stream>>>(
      attnout, wprojT, b_proj, nullptr, out, nullptr, nullptr, 4096, 1024,
      1024);
}